// Round 9
// baseline (282.808 us; speedup 1.0000x reference)
//
#include <hip/hip_runtime.h>

typedef __attribute__((ext_vector_type(8))) short bf16x8;
typedef __attribute__((ext_vector_type(4))) float f32x4;

__device__ __forceinline__ unsigned short f2bf(float f) {
    union { float f; unsigned int u; } v; v.f = f;
    unsigned int u = v.u;
    return (unsigned short)((u + 0x7FFFu + ((u >> 16) & 1u)) >> 16);
}

__device__ __forceinline__ void cp16_g2l(const void* g, void* l) {
    __builtin_amdgcn_global_load_lds(
        (const __attribute__((address_space(1))) unsigned int*)g,
        (__attribute__((address_space(3))) unsigned int*)l, 16, 0, 0);
}

// Single-kernel whole-tree evaluation.
// 512 blocks; block b owns rows [b*R_j, (b+1)*R_j) at every level j (R_j = 2<<j).
// Children of that range are exactly the block's own range at level j+1
// -> zero inter-block dependencies; levels separated by intra-block drains.
// emb image layout (global-row keyed): row Rg, col n ->
//   elem = (Rg>>7)*16384 + (Rg&1)*8192 + ((Rg&127)>>1)*128 + (n ^ ((((Rg&127)>>1)&7)<<3))
// Full 64-row tiles: linear 32KiB global_load_lds DMA in; LDS-bounce coalesced
// 16B stores out (scattered 2B stores cost 4x write traffic + RFO — round 8).
// Partial tiles (R<64): reg-staged in (global-il swizzle src, local-il dest),
// masked stores out.
__global__ __launch_bounds__(256, 2) void k_tree(
    const float* __restrict__ c0, const float* __restrict__ c1,
    const float* __restrict__ c2, const float* __restrict__ c3,
    const float* __restrict__ c4, const float* __restrict__ c5,
    const float* __restrict__ c6, const float* __restrict__ c7,
    const float* __restrict__ c8, const float* __restrict__ c9,
    const float* __restrict__ Wu, const float* __restrict__ bu,
    const float* __restrict__ Wh, const float* __restrict__ bh,
    unsigned short* __restrict__ bufE, unsigned short* __restrict__ bufO,
    float* __restrict__ outF)
{
    // LDS: 32K (A) + 16K (u) + 4K (wu) = 52 KiB
    __shared__ __align__(16) unsigned short A_lds[2][64][128]; // [cc][il][n^swz]
    __shared__ __align__(16) unsigned short u_lds[64][128];    // [i][n^swz] (+ epilogue bounce)
    __shared__ __align__(16) unsigned short wu_lds[8][32][8];  // [nf][l4*16+l15][e]

    const int tid = threadIdx.x, lane = tid & 63, wid = tid >> 6;
    const int l15 = lane & 15, l4 = lane >> 4;

    // ---- persistent W fragments (pinned vs rematerialization) ----
    bf16x8 wreg[2][12];
    #pragma unroll
    for (int nf2 = 0; nf2 < 2; ++nf2) {
        int n = wid * 32 + nf2 * 16 + l15;
        #pragma unroll
        for (int kb = 0; kb < 12; ++kb) {
            const float* wp = Wh + n * 384 + kb * 32 + l4 * 8;
            f32x4 lo = *(const f32x4*)wp;
            f32x4 hi = *(const f32x4*)(wp + 4);
            bf16x8 v;
            #pragma unroll
            for (int e = 0; e < 4; ++e) {
                ((unsigned short*)&v)[e]     = f2bf(lo[e]);
                ((unsigned short*)&v)[e + 4] = f2bf(hi[e]);
            }
            wreg[nf2][kb] = v;
        }
    }
    #pragma unroll
    for (int kb = 0; kb < 12; ++kb)
        asm volatile("" : "+v"(wreg[0][kb]), "+v"(wreg[1][kb]));

    // ---- Wu/bu fragment table in LDS (wave 0 writes) ----
    if (wid == 0 && l4 < 2) {
        #pragma unroll
        for (int nf = 0; nf < 8; ++nf) {
            int n = nf * 16 + l15;
            bf16x8 v = {0, 0, 0, 0, 0, 0, 0, 0};
            if (l4 == 0) {
                #pragma unroll
                for (int k = 0; k < 8; ++k) ((unsigned short*)&v)[k] = f2bf(Wu[n * 8 + k]);
            } else {
                ((unsigned short*)&v)[0] = f2bf(bu[n]);   // bias column (k=8)
            }
            *(bf16x8*)&wu_lds[nf][l4 * 16 + l15][0] = v;
        }
    }
    const float bhv0 = bh[wid * 32 + l15];
    const float bhv1 = bh[wid * 32 + 16 + l15];

    bf16x8 zeroA = {0, 0, 0, 0, 0, 0, 0, 0};
    bf16x8 onesA = zeroA; ((unsigned short*)&onesA)[0] = 0x3F80;  // 1.0 at k=8

    __syncthreads();  // wu_lds visible

    f32x4 cO0 = {0,0,0,0}, cO1 = {0,0,0,0};
    f32x4 cC00 = {0,0,0,0}, cC01 = {0,0,0,0}, cC10 = {0,0,0,0}, cC11 = {0,0,0,0};

    for (int j = 8; j >= 0; --j) {
        const bool LEAF = (j == 8), LAST = (j == 0);
        const int R = 2 << j;                       // rows/block at this level
        const int T = (R >= 64) ? (R >> 6) : 1;     // tiles/block
        const int M = (R < 64) ? R : 64;            // valid rows in (only) tile
        const float* contO;
        switch (j) {
            case 8: contO = c8; break;  case 7: contO = c7; break;
            case 6: contO = c6; break;  case 5: contO = c5; break;
            case 4: contO = c4; break;  case 3: contO = c3; break;
            case 2: contO = c2; break;  case 1: contO = c1; break;
            default: contO = c0; break;
        }
        const unsigned short* eIn  = (j & 1) ? bufE : bufO;
        unsigned short*       eOut = (j & 1) ? bufO : bufE;
        const size_t rowBase  = (size_t)blockIdx.x * (size_t)R;
        const size_t crowBase = rowBase * 2;

        // ---- level prologue: tile-0 inputs ----
        if (!LEAF) {
            if (M == 64) {  // full tile: contiguous 32 KiB linear DMA
                const unsigned short* gb = eIn + (crowBase >> 7) * 16384;
                #pragma unroll
                for (int it = 0; it < 8; ++it) {
                    int q = tid + it * 256;
                    cp16_g2l(gb + (size_t)q * 8, &A_lds[0][0][0] + q * 8);
                }
            } else {
                // partial: reg-staged, swizzle-correct (global-il source, local-il dest)
                const int ilBase = ((int)(crowBase & 127)) >> 1;
                const unsigned short* gb = eIn + (crowBase >> 7) * 16384 + (size_t)ilBase * 128;
                const int per = 16 * M, tot = 32 * M;
                for (int q = tid; q < tot; q += 256) {
                    int cc = (q >= per) ? 1 : 0;
                    int qq = q - (cc ? per : 0);
                    int il_loc = qq >> 4, slot = qq & 15;
                    int il_g = ilBase + il_loc;
                    int kc = slot ^ (il_loc & 7);        // logical k-chunk stored at this dest slot
                    int src_slot = kc ^ (il_g & 7);      // where the producer put it
                    bf16x8 v = *(const bf16x8*)(gb + cc * 8192 + il_loc * 128 + src_slot * 8);
                    *(bf16x8*)(&A_lds[cc][il_loc][slot * 8]) = v;
                }
            }
            __builtin_amdgcn_sched_barrier(0);  // pin: staging issued before contents loads
        }
        if (l4 == 0) {
            size_t row = rowBase + (size_t)(wid * 16 + l15);
            size_t mx = rowBase + R - 1; if (row > mx) row = mx;
            const float* p = contO + row * 8;
            cO0 = *(const f32x4*)p; cO1 = *(const f32x4*)(p + 4);
            if (LEAF) {
                const float* pc = c9 + (crowBase + (size_t)(wid * 32 + l15)) * 8;
                cC00 = *(const f32x4*)pc;         cC01 = *(const f32x4*)(pc + 4);
                cC10 = *(const f32x4*)(pc + 128); cC11 = *(const f32x4*)(pc + 132);
            }
        }

        for (int tt = 0; tt < T; ++tt) {
            // ======== u-phase (own rows) ========
            {
                bf16x8 au = zeroA;
                if (l4 == 0) {
                    #pragma unroll
                    for (int e = 0; e < 4; ++e) {
                        ((unsigned short*)&au)[e]     = f2bf(cO0[e]);
                        ((unsigned short*)&au)[e + 4] = f2bf(cO1[e]);
                    }
                } else if (l4 == 1) au = onesA;
                #pragma unroll
                for (int nf = 0; nf < 8; ++nf) {
                    bf16x8 wv = zeroA;
                    if (l4 < 2) wv = *(const bf16x8*)&wu_lds[nf][l4 * 16 + l15][0];
                    f32x4 z = {0.f, 0.f, 0.f, 0.f};
                    z = __builtin_amdgcn_mfma_f32_16x16x32_bf16(au, wv, z, 0, 0, 0);
                    #pragma unroll
                    for (int r = 0; r < 4; ++r) {
                        int iu = wid * 16 + l4 * 4 + r;
                        int n = nf * 16 + l15;
                        u_lds[iu][n ^ ((iu & 7) << 3)] = f2bf(fmaxf(z[r], 0.f));
                    }
                }
            }
            if (LEAF) {  // child-u directly into A image
                #pragma unroll
                for (int rb = 0; rb < 2; ++rb) {
                    bf16x8 ac = zeroA;
                    if (l4 == 0) {
                        f32x4 a = rb ? cC10 : cC00, b2 = rb ? cC11 : cC01;
                        #pragma unroll
                        for (int e = 0; e < 4; ++e) {
                            ((unsigned short*)&ac)[e]     = f2bf(a[e]);
                            ((unsigned short*)&ac)[e + 4] = f2bf(b2[e]);
                        }
                    } else if (l4 == 1) ac = onesA;
                    #pragma unroll
                    for (int nf = 0; nf < 8; ++nf) {
                        bf16x8 wv = zeroA;
                        if (l4 < 2) wv = *(const bf16x8*)&wu_lds[nf][l4 * 16 + l15][0];
                        f32x4 z = {0.f, 0.f, 0.f, 0.f};
                        z = __builtin_amdgcn_mfma_f32_16x16x32_bf16(ac, wv, z, 0, 0, 0);
                        #pragma unroll
                        for (int r = 0; r < 4; ++r) {
                            int rr = wid * 32 + rb * 16 + l4 * 4 + r;
                            int cc = rr & 1, il = rr >> 1;
                            int n = nf * 16 + l15;
                            A_lds[cc][il][n ^ ((il & 7) << 3)] = f2bf(fmaxf(z[r], 0.f));
                        }
                    }
                }
            }
            // ---- prefetch next tile's contents (clamped; uniform VMEM counts) ----
            {
                int tn = (tt + 1 < T) ? tt + 1 : tt;
                if (l4 == 0) {
                    size_t row = rowBase + (size_t)tn * 64 + (size_t)(wid * 16 + l15);
                    size_t mx = rowBase + R - 1; if (row > mx) row = mx;
                    const float* p = contO + row * 8;
                    cO0 = *(const f32x4*)p; cO1 = *(const f32x4*)(p + 4);
                    if (LEAF) {
                        const float* pc = c9 + (crowBase + (size_t)tn * 128 + (size_t)(wid * 32 + l15)) * 8;
                        cC00 = *(const f32x4*)pc;         cC01 = *(const f32x4*)(pc + 4);
                        cC10 = *(const f32x4*)(pc + 128); cC11 = *(const f32x4*)(pc + 132);
                    }
                }
            }

            // ======== phase barrier: A ready (counted vmcnt), u visible ========
            if (!LEAF) {
                if (tt == 0) asm volatile("s_waitcnt vmcnt(2)" ::: "memory");  // drain prologue staging; leave 2 contents loads
                else         asm volatile("s_waitcnt vmcnt(6)" ::: "memory");  // drain 8 DMA; leave 4 stores + 2 contents loads
            }
            asm volatile("s_waitcnt lgkmcnt(0)" ::: "memory");
            __builtin_amdgcn_sched_barrier(0);
            __builtin_amdgcn_s_barrier();
            __builtin_amdgcn_sched_barrier(0);

            // ======== main GEMM: K=384 = [child0 | child1 | u] ========
            f32x4 acc[4][2];
            #pragma unroll
            for (int mf = 0; mf < 4; ++mf) {
                acc[mf][0] = (f32x4){bhv0, bhv0, bhv0, bhv0};
                acc[mf][1] = (f32x4){bhv1, bhv1, bhv1, bhv1};
            }
            __builtin_amdgcn_s_setprio(1);
            #pragma unroll
            for (int kb = 0; kb < 8; ++kb) {
                bf16x8 af[4];
                #pragma unroll
                for (int mf = 0; mf < 4; ++mf) {
                    int i = mf * 16 + l15;
                    af[mf] = *(const bf16x8*)&A_lds[kb >> 2][i][((((kb & 3) * 4) + l4) ^ (i & 7)) * 8];
                }
                #pragma unroll
                for (int mf = 0; mf < 4; ++mf) {
                    acc[mf][0] = __builtin_amdgcn_mfma_f32_16x16x32_bf16(af[mf], wreg[0][kb], acc[mf][0], 0, 0, 0);
                    acc[mf][1] = __builtin_amdgcn_mfma_f32_16x16x32_bf16(af[mf], wreg[1][kb], acc[mf][1], 0, 0, 0);
                }
            }
            __builtin_amdgcn_s_setprio(0);

            // A consumed -> barrier, then prefetch next tile's A DMA (full tiles only)
            if (!LEAF) {
                asm volatile("s_waitcnt lgkmcnt(0)" ::: "memory");
                __builtin_amdgcn_sched_barrier(0);
                __builtin_amdgcn_s_barrier();
                __builtin_amdgcn_sched_barrier(0);
                if (tt + 1 < T) {
                    const unsigned short* gb = eIn + ((crowBase + (size_t)(tt + 1) * 128) >> 7) * 16384;
                    #pragma unroll
                    for (int it = 0; it < 8; ++it) {
                        int q = tid + it * 256;
                        cp16_g2l(gb + (size_t)q * 8, &A_lds[0][0][0] + q * 8);
                    }
                    __builtin_amdgcn_sched_barrier(0);
                }
            }

            __builtin_amdgcn_s_setprio(1);
            #pragma unroll
            for (int kb = 8; kb < 12; ++kb) {
                bf16x8 af[4];
                #pragma unroll
                for (int mf = 0; mf < 4; ++mf) {
                    int i = mf * 16 + l15;
                    af[mf] = *(const bf16x8*)&u_lds[i][((((kb - 8) * 4) + l4) ^ (i & 7)) * 8];
                }
                #pragma unroll
                for (int mf = 0; mf < 4; ++mf) {
                    acc[mf][0] = __builtin_amdgcn_mfma_f32_16x16x32_bf16(af[mf], wreg[0][kb], acc[mf][0], 0, 0, 0);
                    acc[mf][1] = __builtin_amdgcn_mfma_f32_16x16x32_bf16(af[mf], wreg[1][kb], acc[mf][1], 0, 0, 0);
                }
            }
            __builtin_amdgcn_s_setprio(0);

            // ======== epilogue ========
            if (LAST) {
                #pragma unroll
                for (int mf = 0; mf < 4; ++mf)
                    #pragma unroll
                    for (int nf2 = 0; nf2 < 2; ++nf2)
                        #pragma unroll
                        for (int r = 0; r < 4; ++r) {
                            int i = mf * 16 + l4 * 4 + r;
                            if (i < M) {
                                int n = wid * 32 + nf2 * 16 + l15;
                                outF[(rowBase + i) * 128 + n] = fmaxf(acc[mf][nf2][r], 0.f);
                            }
                        }
            } else if (M == 64) {
                // full tile: bounce through u_lds (dead after kb8-11) -> coalesced 16B stores
                asm volatile("s_waitcnt lgkmcnt(0)" ::: "memory");
                __builtin_amdgcn_sched_barrier(0);
                __builtin_amdgcn_s_barrier();        // [A] all u_lds reads done
                unsigned short* ep = &u_lds[0][0];
                #pragma unroll
                for (int mf = 0; mf < 4; ++mf)
                    #pragma unroll
                    for (int nf2 = 0; nf2 < 2; ++nf2)
                        #pragma unroll
                        for (int r = 0; r < 4; ++r) {
                            int i = mf * 16 + l4 * 4 + r;
                            int n = wid * 32 + nf2 * 16 + l15;
                            int row = (i & 1) * 32 + (i >> 1);   // image row within tile
                            ep[row * 128 + (n ^ (((i >> 1) & 7) << 3))] = f2bf(fmaxf(acc[mf][nf2][r], 0.f));
                        }
                asm volatile("s_waitcnt lgkmcnt(0)" ::: "memory");
                __builtin_amdgcn_s_barrier();        // [B] ep writes visible
                bf16x8 ev0 = *(const bf16x8*)&ep[(0 * 256 + tid) * 8];
                bf16x8 ev1 = *(const bf16x8*)&ep[(1 * 256 + tid) * 8];
                bf16x8 ev2 = *(const bf16x8*)&ep[(2 * 256 + tid) * 8];
                bf16x8 ev3 = *(const bf16x8*)&ep[(3 * 256 + tid) * 8];
                asm volatile("s_waitcnt lgkmcnt(0)" ::: "memory");
                __builtin_amdgcn_sched_barrier(0);
                __builtin_amdgcn_s_barrier();        // [C] reads done -> u_lds free next iter
                size_t tIdx = (rowBase >> 6) + (size_t)tt;       // global 64-row tile index
                size_t gbase = (tIdx >> 1) * 16384 + (tIdx & 1) * 4096;
                unsigned short* gp = eOut + gbase;
                *(bf16x8*)(gp + (size_t)((0 * 256 + tid) >> 9) * 8192 + ((0 * 256 + tid) & 511) * 8) = ev0;
                *(bf16x8*)(gp + (size_t)((1 * 256 + tid) >> 9) * 8192 + ((1 * 256 + tid) & 511) * 8) = ev1;
                *(bf16x8*)(gp + (size_t)((2 * 256 + tid) >> 9) * 8192 + ((2 * 256 + tid) & 511) * 8) = ev2;
                *(bf16x8*)(gp + (size_t)((3 * 256 + tid) >> 9) * 8192 + ((3 * 256 + tid) & 511) * 8) = ev3;
            } else {               // partial tile: masked (tiny: levels j<=4 sum ~7.5 MB)
                #pragma unroll
                for (int mf = 0; mf < 4; ++mf)
                    #pragma unroll
                    for (int nf2 = 0; nf2 < 2; ++nf2)
                        #pragma unroll
                        for (int r = 0; r < 4; ++r) {
                            int i = mf * 16 + l4 * 4 + r;
                            if (i < M) {
                                size_t Rg = rowBase + i;
                                int n = wid * 32 + nf2 * 16 + l15;
                                int rr = (int)(Rg & 127);
                                size_t e = (Rg >> 7) * 16384 + (size_t)((rr & 1) * 8192)
                                         + (size_t)((rr >> 1) * 128)
                                         + (size_t)(n ^ (((rr >> 1) & 7) << 3));
                                eOut[e] = f2bf(fmaxf(acc[mf][nf2][r], 0.f));
                            }
                        }
            }

            // ======== post barrier: u_lds/A_lds free for next tile's writes ========
            asm volatile("s_waitcnt lgkmcnt(0)" ::: "memory");
            __builtin_amdgcn_sched_barrier(0);
            __builtin_amdgcn_s_barrier();
        }

        // ---- level end: image stores visible before next level's staging reads ----
        asm volatile("s_waitcnt vmcnt(0) lgkmcnt(0)" ::: "memory");
        __builtin_amdgcn_sched_barrier(0);
        __builtin_amdgcn_s_barrier();
    }
}

extern "C" void kernel_launch(void* const* d_in, const int* in_sizes, int n_in,
                              void* d_out, int out_size, void* d_ws, size_t ws_size,
                              hipStream_t stream) {
    const float* c[10];
    for (int j = 0; j < 10; ++j) c[j] = (const float*)d_in[j];
    const float* Wu = (const float*)d_in[19];
    const float* bu = (const float*)d_in[20];
    const float* Wh = (const float*)d_in[21];
    const float* bh = (const float*)d_in[22];

    unsigned short* bufE = (unsigned short*)d_ws;                        // 64 MiB (even-level embs)
    unsigned short* bufO = (unsigned short*)((char*)d_ws + (64u << 20)); // 32 MiB (odd-level embs)

    k_tree<<<512, 256, 0, stream>>>(c[0], c[1], c[2], c[3], c[4], c[5], c[6], c[7], c[8], c[9],
                                    Wu, bu, Wh, bh, bufE, bufO, (float*)d_out);
}

// Round 10
// 205.572 us; speedup vs baseline: 1.3757x; 1.3757x over previous
//
#include <hip/hip_runtime.h>
#include <hip/hip_bf16.h>

typedef __attribute__((ext_vector_type(8))) short bf16x8;
typedef __attribute__((ext_vector_type(4))) float f32x4;

__device__ __forceinline__ unsigned short f2bf(float f) {
    __hip_bfloat16 h = __float2bfloat16(f);   // RTNE, compiler emits v_cvt_pk_bf16_f32 for pairs
    union { __hip_bfloat16 h; unsigned short u; } v; v.h = h;
    return v.u;
}

__device__ __forceinline__ void cp16_g2l(const void* g, void* l) {
    __builtin_amdgcn_global_load_lds(
        (const __attribute__((address_space(1))) unsigned int*)g,
        (__attribute__((address_space(3))) unsigned int*)l, 16, 0, 0);
}

// ---- one-time: W_h f32 [128][384] -> plain bf16 row-major image in ws ----
__global__ __launch_bounds__(384) void k_cvtW(const float* __restrict__ Wh,
                                              unsigned short* __restrict__ Wbf) {
    int n = blockIdx.x, k = threadIdx.x;
    Wbf[n * 384 + k] = f2bf(Wh[n * 384 + k]);
}

// Block tile: 64 own rows x 128 cols, 4 waves (wave = 64 rows x 32-col quarter).
// W_h in registers from bf16 image (pinned). Wu/bu fragment table in LDS.
// Contents prefetched one tile ahead into u-MFMA A-fragment lanes. A-tile DMA
// prefetched one tile ahead, drained by counted vmcnt at the phase barrier.
template<int LEAF, int LAST>
__global__ __launch_bounds__(256, 2) void k_level(
    const unsigned short* __restrict__ embIn,
    const float* __restrict__ contO,   // [n][8] own contents
    const float* __restrict__ contC,   // [2n][8] child contents (LEAF only)
    const unsigned short* __restrict__ Wbf, // bf16 W image [128*384]
    const float* __restrict__ Wu,      // [128][8]
    const float* __restrict__ bu,      // [128]
    const float* __restrict__ bh,      // [128]
    unsigned short* __restrict__ embOut, // child-image layout
    float* __restrict__ outF,          // row-major f32 (LAST)
    int n_nodes)
{
    // LDS: 32K (A) + 16K (u) + 4K (wu) = 52 KiB -> 3 blocks/CU
    __shared__ __align__(16) unsigned short A_lds[2][64][128]; // [cc][il][n^swz]
    __shared__ __align__(16) unsigned short u_lds[64][128];    // [i][n^swz] (+ epilogue bounce)
    __shared__ __align__(16) unsigned short wu_lds[8][32][8];  // [nf][l4*16+l15][e]

    const int t = threadIdx.x, lane = t & 63, wid = t >> 6;
    const int l15 = lane & 15, l4 = lane >> 4;

    // ---- persistent W fragments: 24 x 16B loads from the bf16 image, pinned ----
    bf16x8 wreg[2][12];
    #pragma unroll
    for (int nf2 = 0; nf2 < 2; ++nf2) {
        int n = wid * 32 + nf2 * 16 + l15;
        #pragma unroll
        for (int kb = 0; kb < 12; ++kb)
            wreg[nf2][kb] = *reinterpret_cast<const bf16x8*>(Wbf + n * 384 + kb * 32 + l4 * 8);
    }
    #pragma unroll
    for (int kb = 0; kb < 12; ++kb)
        asm volatile("" : "+v"(wreg[0][kb]), "+v"(wreg[1][kb]));

    // ---- Wu/bu fragment table (B-op of K=32-padded u-GEMM), written by wave 0 ----
    if (wid == 0 && l4 < 2) {
        #pragma unroll
        for (int nf = 0; nf < 8; ++nf) {
            int n = nf * 16 + l15;
            bf16x8 v = {0, 0, 0, 0, 0, 0, 0, 0};
            if (l4 == 0) {
                #pragma unroll
                for (int k = 0; k < 8; ++k) ((unsigned short*)&v)[k] = f2bf(Wu[n * 8 + k]);
            } else {
                ((unsigned short*)&v)[0] = f2bf(bu[n]);   // bias column (k=8)
            }
            *(bf16x8*)&wu_lds[nf][l4 * 16 + l15][0] = v;
        }
    }
    const float bhv0 = bh[wid * 32 + l15];
    const float bhv1 = bh[wid * 32 + 16 + l15];

    bf16x8 zeroA = {0, 0, 0, 0, 0, 0, 0, 0};
    bf16x8 onesA = zeroA; ((unsigned short*)&onesA)[0] = 0x3F80;  // 1.0 at k=8

    const int ntiles = n_nodes >> 6;
    const int stride = gridDim.x;
    const int tile0 = blockIdx.x;
    if (tile0 >= ntiles) return;

    // ---- contents prefetch registers (A-fragment lanes: l4==0 holds the row) ----
    f32x4 cO0 = {0,0,0,0}, cO1 = {0,0,0,0};
    f32x4 cC00 = {0,0,0,0}, cC01 = {0,0,0,0}, cC10 = {0,0,0,0}, cC11 = {0,0,0,0};

    // ---- prologue: tile0 A DMA + contents ----
    if (!LEAF) {
        const unsigned short* src = embIn + (size_t)tile0 * 16384;
        #pragma unroll
        for (int it = 0; it < 8; ++it) {
            int q = t + it * 256;
            cp16_g2l(src + q * 8, &A_lds[0][0][0] + q * 8);
        }
    }
    if (l4 == 0) {
        const float* p = contO + ((size_t)tile0 * 64 + wid * 16 + l15) * 8;
        cO0 = *(const f32x4*)p; cO1 = *(const f32x4*)(p + 4);
        if (LEAF) {
            const float* pc = contC + ((size_t)tile0 * 128 + wid * 32 + l15) * 8;
            cC00 = *(const f32x4*)pc;         cC01 = *(const f32x4*)(pc + 4);
            cC10 = *(const f32x4*)(pc + 128); cC11 = *(const f32x4*)(pc + 132);
        }
    }
    __syncthreads();  // drains prologue DMA/loads + wu_lds visible

    for (int tile = tile0; tile < ntiles; tile += stride) {
        const int tnext = tile + stride;

        // ======== u-phase: from regs, no LDS staging ========
        {
            bf16x8 au = zeroA;
            if (l4 == 0) {
                #pragma unroll
                for (int e = 0; e < 4; ++e) {
                    ((unsigned short*)&au)[e]     = f2bf(cO0[e]);
                    ((unsigned short*)&au)[e + 4] = f2bf(cO1[e]);
                }
            } else if (l4 == 1) au = onesA;
            #pragma unroll
            for (int nf = 0; nf < 8; ++nf) {
                bf16x8 wv = zeroA;
                if (l4 < 2) wv = *(const bf16x8*)&wu_lds[nf][l4 * 16 + l15][0];
                f32x4 z = {0.f, 0.f, 0.f, 0.f};
                z = __builtin_amdgcn_mfma_f32_16x16x32_bf16(au, wv, z, 0, 0, 0);
                #pragma unroll
                for (int r = 0; r < 4; ++r) {
                    int iu = wid * 16 + l4 * 4 + r;
                    int n = nf * 16 + l15;
                    u_lds[iu][n ^ ((iu & 7) << 3)] = f2bf(fmaxf(z[r], 0.f));
                }
            }
        }
        if (LEAF) {
            #pragma unroll
            for (int rb = 0; rb < 2; ++rb) {
                bf16x8 ac = zeroA;
                if (l4 == 0) {
                    f32x4 a = rb ? cC10 : cC00, b2 = rb ? cC11 : cC01;
                    #pragma unroll
                    for (int e = 0; e < 4; ++e) {
                        ((unsigned short*)&ac)[e]     = f2bf(a[e]);
                        ((unsigned short*)&ac)[e + 4] = f2bf(b2[e]);
                    }
                } else if (l4 == 1) ac = onesA;
                #pragma unroll
                for (int nf = 0; nf < 8; ++nf) {
                    bf16x8 wv = zeroA;
                    if (l4 < 2) wv = *(const bf16x8*)&wu_lds[nf][l4 * 16 + l15][0];
                    f32x4 z = {0.f, 0.f, 0.f, 0.f};
                    z = __builtin_amdgcn_mfma_f32_16x16x32_bf16(ac, wv, z, 0, 0, 0);
                    #pragma unroll
                    for (int r = 0; r < 4; ++r) {
                        int rr = wid * 32 + rb * 16 + l4 * 4 + r;  // local child row
                        int cc = rr & 1, il = rr >> 1;
                        int n = nf * 16 + l15;
                        A_lds[cc][il][n ^ ((il & 7) << 3)] = f2bf(fmaxf(z[r], 0.f));
                    }
                }
            }
        }

        // ---- prefetch next tile's contents (issue-early, consumed next iter) ----
        if (tnext < ntiles && l4 == 0) {
            const float* p = contO + ((size_t)tnext * 64 + wid * 16 + l15) * 8;
            cO0 = *(const f32x4*)p; cO1 = *(const f32x4*)(p + 4);
            if (LEAF) {
                const float* pc = contC + ((size_t)tnext * 128 + wid * 32 + l15) * 8;
                cC00 = *(const f32x4*)pc;         cC01 = *(const f32x4*)(pc + 4);
                cC10 = *(const f32x4*)(pc + 128); cC11 = *(const f32x4*)(pc + 132);
            }
        }

        // ======== phase barrier: A slabs ready (counted vmcnt), u/A visible ========
        if (!LEAF) asm volatile("s_waitcnt vmcnt(4)" ::: "memory");  // drains prev-issued DMA; leaves stores
        asm volatile("s_waitcnt lgkmcnt(0)" ::: "memory");
        __builtin_amdgcn_sched_barrier(0);
        __builtin_amdgcn_s_barrier();
        __builtin_amdgcn_sched_barrier(0);

        // ======== main GEMM: K=384 = [child0 | child1 | u] ========
        f32x4 acc[4][2];
        #pragma unroll
        for (int mf = 0; mf < 4; ++mf) {
            acc[mf][0] = (f32x4){bhv0, bhv0, bhv0, bhv0};
            acc[mf][1] = (f32x4){bhv1, bhv1, bhv1, bhv1};
        }

        #pragma unroll
        for (int kb = 0; kb < 8; ++kb) {   // A slabs
            bf16x8 af[4];
            #pragma unroll
            for (int mf = 0; mf < 4; ++mf) {
                int i = mf * 16 + l15;
                af[mf] = *(const bf16x8*)&A_lds[kb >> 2][i][((((kb & 3) * 4) + l4) ^ (i & 7)) * 8];
            }
            #pragma unroll
            for (int mf = 0; mf < 4; ++mf) {
                acc[mf][0] = __builtin_amdgcn_mfma_f32_16x16x32_bf16(af[mf], wreg[0][kb], acc[mf][0], 0, 0, 0);
                acc[mf][1] = __builtin_amdgcn_mfma_f32_16x16x32_bf16(af[mf], wreg[1][kb], acc[mf][1], 0, 0, 0);
            }
        }

        // A fully consumed -> barrier, then prefetch next tile's A DMA
        if (!LEAF) {
            asm volatile("s_waitcnt lgkmcnt(0)" ::: "memory");
            __builtin_amdgcn_sched_barrier(0);
            __builtin_amdgcn_s_barrier();
            __builtin_amdgcn_sched_barrier(0);
            if (tnext < ntiles) {
                const unsigned short* src = embIn + (size_t)tnext * 16384;
                #pragma unroll
                for (int it = 0; it < 8; ++it) {
                    int q = t + it * 256;
                    cp16_g2l(src + q * 8, &A_lds[0][0][0] + q * 8);
                }
            }
        }

        #pragma unroll
        for (int kb = 8; kb < 12; ++kb) {  // u
            bf16x8 af[4];
            #pragma unroll
            for (int mf = 0; mf < 4; ++mf) {
                int i = mf * 16 + l15;
                af[mf] = *(const bf16x8*)&u_lds[i][((((kb - 8) * 4) + l4) ^ (i & 7)) * 8];
            }
            #pragma unroll
            for (int mf = 0; mf < 4; ++mf) {
                acc[mf][0] = __builtin_amdgcn_mfma_f32_16x16x32_bf16(af[mf], wreg[0][kb], acc[mf][0], 0, 0, 0);
                acc[mf][1] = __builtin_amdgcn_mfma_f32_16x16x32_bf16(af[mf], wreg[1][kb], acc[mf][1], 0, 0, 0);
            }
        }

        // ======== epilogue ========
        if (LAST) {
            #pragma unroll
            for (int mf = 0; mf < 4; ++mf)
                #pragma unroll
                for (int nf2 = 0; nf2 < 2; ++nf2)
                    #pragma unroll
                    for (int r = 0; r < 4; ++r) {
                        int i = mf * 16 + l4 * 4 + r;
                        int n = wid * 32 + nf2 * 16 + l15;
                        outF[(size_t)(tile * 64 + i) * 128 + n] = fmaxf(acc[mf][nf2][r], 0.f);
                    }
        } else {
            // u_lds reads (kb8-11) done by all waves before reuse as bounce buffer
            asm volatile("s_waitcnt lgkmcnt(0)" ::: "memory");
            __builtin_amdgcn_sched_barrier(0);
            __builtin_amdgcn_s_barrier();        // [A]
            unsigned short* ep = &u_lds[0][0];
            #pragma unroll
            for (int mf = 0; mf < 4; ++mf)
                #pragma unroll
                for (int nf2 = 0; nf2 < 2; ++nf2)
                    #pragma unroll
                    for (int r = 0; r < 4; ++r) {
                        int i = mf * 16 + l4 * 4 + r;
                        int n = wid * 32 + nf2 * 16 + l15;
                        int row = (i & 1) * 32 + (i >> 1);   // image row within tile
                        ep[row * 128 + (n ^ (((i >> 1) & 7) << 3))] = f2bf(fmaxf(acc[mf][nf2][r], 0.f));
                    }
            asm volatile("s_waitcnt lgkmcnt(0)" ::: "memory");
            __builtin_amdgcn_s_barrier();        // [B] ep writes visible
            bf16x8 ev0 = *(const bf16x8*)&ep[(0 * 256 + t) * 8];
            bf16x8 ev1 = *(const bf16x8*)&ep[(1 * 256 + t) * 8];
            bf16x8 ev2 = *(const bf16x8*)&ep[(2 * 256 + t) * 8];
            bf16x8 ev3 = *(const bf16x8*)&ep[(3 * 256 + t) * 8];
            asm volatile("s_waitcnt lgkmcnt(0)" ::: "memory");
            __builtin_amdgcn_sched_barrier(0);
            __builtin_amdgcn_s_barrier();        // [C] reads done -> u_lds free next iter
            size_t gbase = (size_t)(tile >> 1) * 16384 + (size_t)(tile & 1) * 4096;
            unsigned short* gp = embOut + gbase;
            *(bf16x8*)(gp + (size_t)((0 * 256 + t) >> 9) * 8192 + ((0 * 256 + t) & 511) * 8) = ev0;
            *(bf16x8*)(gp + (size_t)((1 * 256 + t) >> 9) * 8192 + ((1 * 256 + t) & 511) * 8) = ev1;
            *(bf16x8*)(gp + (size_t)((2 * 256 + t) >> 9) * 8192 + ((2 * 256 + t) & 511) * 8) = ev2;
            *(bf16x8*)(gp + (size_t)((3 * 256 + t) >> 9) * 8192 + ((3 * 256 + t) & 511) * 8) = ev3;
        }
    }
}

extern "C" void kernel_launch(void* const* d_in, const int* in_sizes, int n_in,
                              void* d_out, int out_size, void* d_ws, size_t ws_size,
                              hipStream_t stream) {
    const float* contents[10];
    for (int j = 0; j < 10; ++j) contents[j] = (const float*)d_in[j];
    const float* Wu = (const float*)d_in[19];
    const float* bu = (const float*)d_in[20];
    const float* Wh = (const float*)d_in[21];
    const float* bh = (const float*)d_in[22];

    unsigned short* Wbf  = (unsigned short*)d_ws;                                     // 96 KiB
    unsigned short* bufE = (unsigned short*)((char*)d_ws + (1u << 20));               // 64 MiB (even-level embs)
    unsigned short* bufO = (unsigned short*)((char*)d_ws + (1u << 20) + (64u << 20)); // 32 MiB (odd-level embs)

    k_cvtW<<<128, 384, 0, stream>>>(Wh, Wbf);

    // level 8 (leaf-fused): children = relu(contents_9 @ Wu^T + bu) computed in-kernel
    {
        int ntiles = (1024 << 8) >> 6;   // 4096
        int grid = ntiles < 768 ? ntiles : 768;
        k_level<1, 0><<<grid, 256, 0, stream>>>(nullptr, contents[8], contents[9], Wbf,
                                                Wu, bu, bh, bufE, nullptr, 1024 << 8);
    }
    // levels 7..1
    for (int j = 7; j >= 1; --j) {
        int n = 1024 << j;
        const unsigned short* in = (j & 1) ? bufE : bufO;  // emb_{j+1}
        unsigned short* outp     = (j & 1) ? bufO : bufE;  // emb_j
        int ntiles = n >> 6;
        int grid = ntiles < 768 ? ntiles : 768;
        k_level<0, 0><<<grid, 256, 0, stream>>>(in, contents[j], nullptr, Wbf,
                                                Wu, bu, bh, outp, nullptr, n);
    }
    // level 0 -> f32 output (16 tiles)
    k_level<0, 1><<<16, 256, 0, stream>>>(bufO, contents[0], nullptr, Wbf,
                                          Wu, bu, bh, nullptr, (float*)d_out, 1024);
}

// Round 11
// 197.637 us; speedup vs baseline: 1.4309x; 1.0402x over previous
//
#include <hip/hip_runtime.h>
#include <hip/hip_bf16.h>

typedef __attribute__((ext_vector_type(8))) short bf16x8;
typedef __attribute__((ext_vector_type(4))) float f32x4;

__device__ __forceinline__ unsigned short f2bf(float f) {
    __hip_bfloat16 h = __float2bfloat16(f);   // RTNE; compiler emits v_cvt_pk_bf16_f32 for pairs
    union { __hip_bfloat16 h; unsigned short u; } v; v.h = h;
    return v.u;
}

__device__ __forceinline__ void cp16_g2l(const void* g, void* l) {
    __builtin_amdgcn_global_load_lds(
        (const __attribute__((address_space(1))) unsigned int*)g,
        (__attribute__((address_space(3))) unsigned int*)l, 16, 0, 0);
}

// ---- one-time: W_h f32 [128][384] -> plain bf16 row-major image in ws ----
__global__ __launch_bounds__(384) void k_cvtW(const float* __restrict__ Wh,
                                              unsigned short* __restrict__ Wbf) {
    int n = blockIdx.x, k = threadIdx.x;
    Wbf[n * 384 + k] = f2bf(Wh[n * 384 + k]);
}

// Block tile: 64 own rows x 128 cols, EIGHT waves (wave = 64 rows x 16-col slice).
// Per-wave work halved vs the 4-wave version: more resident waves (16/CU by the
// 128-VGPR rule) hide the u-phase->barrier->GEMM->epilogue latency chain via TLP.
// W_h slice in registers (48 VGPR, pinned). Wu/bu fragment table in LDS.
// Contents prefetched one tile ahead into u-MFMA A-fragment lanes. A-tile DMA
// prefetched one tile ahead, drained by counted vmcnt at the phase barrier.
template<int LEAF, int LAST>
__global__ __launch_bounds__(512, 4) void k_level(
    const unsigned short* __restrict__ embIn,
    const float* __restrict__ contO,   // [n][8] own contents
    const float* __restrict__ contC,   // [2n][8] child contents (LEAF only)
    const unsigned short* __restrict__ Wbf, // bf16 W image [128*384]
    const float* __restrict__ Wu,      // [128][8]
    const float* __restrict__ bu,      // [128]
    const float* __restrict__ bh,      // [128]
    unsigned short* __restrict__ embOut, // child-image layout
    float* __restrict__ outF,          // row-major f32 (LAST)
    int n_nodes)
{
    // LDS: 32K (A) + 16K (u) + 4K (wu) = 52 KiB -> 2 blocks/CU (16 waves)
    __shared__ __align__(16) unsigned short A_lds[2][64][128]; // [cc][il][n^swz]
    __shared__ __align__(16) unsigned short u_lds[64][128];    // [i][n^swz] (+ epilogue bounce)
    __shared__ __align__(16) unsigned short wu_lds[8][32][8];  // [nf][l4*16+l15][e]

    const int t = threadIdx.x, lane = t & 63, wid = t >> 6;    // 8 waves
    const int l15 = lane & 15, l4 = lane >> 4;
    const int wrow = wid & 3;        // u-phase row quarter (rows wrow*16..+16)
    const int wcolh = wid >> 2;      // u-phase col half (cols wcolh*64..+64)

    // ---- persistent W fragments: wave's 16-col slice, 12 K-blocks (48 VGPR) ----
    bf16x8 wreg[12];
    {
        int n = wid * 16 + l15;
        #pragma unroll
        for (int kb = 0; kb < 12; ++kb)
            wreg[kb] = *reinterpret_cast<const bf16x8*>(Wbf + n * 384 + kb * 32 + l4 * 8);
    }
    #pragma unroll
    for (int kb = 0; kb < 12; ++kb)
        asm volatile("" : "+v"(wreg[kb]));

    // ---- Wu/bu fragment table (B-op of K=32-padded u-GEMM), written by wave 0 ----
    if (wid == 0 && l4 < 2) {
        #pragma unroll
        for (int nf = 0; nf < 8; ++nf) {
            int n = nf * 16 + l15;
            bf16x8 v = {0, 0, 0, 0, 0, 0, 0, 0};
            if (l4 == 0) {
                #pragma unroll
                for (int k = 0; k < 8; ++k) ((unsigned short*)&v)[k] = f2bf(Wu[n * 8 + k]);
            } else {
                ((unsigned short*)&v)[0] = f2bf(bu[n]);   // bias column (k=8)
            }
            *(bf16x8*)&wu_lds[nf][l4 * 16 + l15][0] = v;
        }
    }
    const float bhv = bh[wid * 16 + l15];

    bf16x8 zeroA = {0, 0, 0, 0, 0, 0, 0, 0};
    bf16x8 onesA = zeroA; ((unsigned short*)&onesA)[0] = 0x3F80;  // 1.0 at k=8

    const int ntiles = n_nodes >> 6;
    const int stride = gridDim.x;
    const int tile0 = blockIdx.x;
    if (tile0 >= ntiles) return;

    // ---- contents prefetch registers (A-fragment lanes: l4==0 holds the row) ----
    f32x4 cO0 = {0,0,0,0}, cO1 = {0,0,0,0};
    f32x4 cC00 = {0,0,0,0}, cC01 = {0,0,0,0}, cC10 = {0,0,0,0}, cC11 = {0,0,0,0};

    // ---- prologue: tile0 A DMA + contents ----
    if (!LEAF) {
        const unsigned short* src = embIn + (size_t)tile0 * 16384;
        #pragma unroll
        for (int it = 0; it < 4; ++it) {
            int q = t + it * 512;
            cp16_g2l(src + q * 8, &A_lds[0][0][0] + q * 8);
        }
    }
    if (l4 == 0) {
        const float* p = contO + ((size_t)tile0 * 64 + wrow * 16 + l15) * 8;
        cO0 = *(const f32x4*)p; cO1 = *(const f32x4*)(p + 4);
        if (LEAF) {
            const float* pc = contC + ((size_t)tile0 * 128 + wrow * 32 + l15) * 8;
            cC00 = *(const f32x4*)pc;         cC01 = *(const f32x4*)(pc + 4);
            cC10 = *(const f32x4*)(pc + 128); cC11 = *(const f32x4*)(pc + 132);
        }
    }
    __syncthreads();  // drains prologue DMA/loads + wu_lds visible

    for (int tile = tile0; tile < ntiles; tile += stride) {
        const int tnext = tile + stride;

        // ======== u-phase: rows wrow*16..+16, cols wcolh*64..+64 (4 MFMA) ========
        {
            bf16x8 au = zeroA;
            if (l4 == 0) {
                #pragma unroll
                for (int e = 0; e < 4; ++e) {
                    ((unsigned short*)&au)[e]     = f2bf(cO0[e]);
                    ((unsigned short*)&au)[e + 4] = f2bf(cO1[e]);
                }
            } else if (l4 == 1) au = onesA;
            #pragma unroll
            for (int nfi = 0; nfi < 4; ++nfi) {
                int nf = wcolh * 4 + nfi;
                bf16x8 wv = zeroA;
                if (l4 < 2) wv = *(const bf16x8*)&wu_lds[nf][l4 * 16 + l15][0];
                f32x4 z = {0.f, 0.f, 0.f, 0.f};
                z = __builtin_amdgcn_mfma_f32_16x16x32_bf16(au, wv, z, 0, 0, 0);
                #pragma unroll
                for (int r = 0; r < 4; ++r) {
                    int iu = wrow * 16 + l4 * 4 + r;
                    int n = nf * 16 + l15;
                    u_lds[iu][n ^ ((iu & 7) << 3)] = f2bf(fmaxf(z[r], 0.f));
                }
            }
        }
        if (LEAF) {  // child-u: child rows wrow*32..+32, cols wcolh*64..+64 (8 MFMA)
            #pragma unroll
            for (int rb = 0; rb < 2; ++rb) {
                bf16x8 ac = zeroA;
                if (l4 == 0) {
                    f32x4 a = rb ? cC10 : cC00, b2 = rb ? cC11 : cC01;
                    #pragma unroll
                    for (int e = 0; e < 4; ++e) {
                        ((unsigned short*)&ac)[e]     = f2bf(a[e]);
                        ((unsigned short*)&ac)[e + 4] = f2bf(b2[e]);
                    }
                } else if (l4 == 1) ac = onesA;
                #pragma unroll
                for (int nfi = 0; nfi < 4; ++nfi) {
                    int nf = wcolh * 4 + nfi;
                    bf16x8 wv = zeroA;
                    if (l4 < 2) wv = *(const bf16x8*)&wu_lds[nf][l4 * 16 + l15][0];
                    f32x4 z = {0.f, 0.f, 0.f, 0.f};
                    z = __builtin_amdgcn_mfma_f32_16x16x32_bf16(ac, wv, z, 0, 0, 0);
                    #pragma unroll
                    for (int r = 0; r < 4; ++r) {
                        int rr = wrow * 32 + rb * 16 + l4 * 4 + r;  // local child row
                        int cc = rr & 1, il = rr >> 1;
                        int n = nf * 16 + l15;
                        A_lds[cc][il][n ^ ((il & 7) << 3)] = f2bf(fmaxf(z[r], 0.f));
                    }
                }
            }
        }

        // ---- prefetch next tile's contents (issue-early, consumed next iter) ----
        if (tnext < ntiles && l4 == 0) {
            const float* p = contO + ((size_t)tnext * 64 + wrow * 16 + l15) * 8;
            cO0 = *(const f32x4*)p; cO1 = *(const f32x4*)(p + 4);
            if (LEAF) {
                const float* pc = contC + ((size_t)tnext * 128 + wrow * 32 + l15) * 8;
                cC00 = *(const f32x4*)pc;         cC01 = *(const f32x4*)(pc + 4);
                cC10 = *(const f32x4*)(pc + 128); cC11 = *(const f32x4*)(pc + 132);
            }
        }

        // ======== phase barrier: A slabs ready (counted vmcnt), u/A visible ========
        if (!LEAF) asm volatile("s_waitcnt vmcnt(4)" ::: "memory");  // drain 4 DMA; leave 2 stores + 2 contents
        asm volatile("s_waitcnt lgkmcnt(0)" ::: "memory");
        __builtin_amdgcn_sched_barrier(0);
        __builtin_amdgcn_s_barrier();
        __builtin_amdgcn_sched_barrier(0);

        // ======== main GEMM: K=384 = [child0 | child1 | u], wave cols wid*16..+16 ========
        f32x4 acc[4];
        #pragma unroll
        for (int mf = 0; mf < 4; ++mf) acc[mf] = (f32x4){bhv, bhv, bhv, bhv};

        #pragma unroll
        for (int kb = 0; kb < 8; ++kb) {   // A slabs
            bf16x8 af[4];
            #pragma unroll
            for (int mf = 0; mf < 4; ++mf) {
                int i = mf * 16 + l15;
                af[mf] = *(const bf16x8*)&A_lds[kb >> 2][i][((((kb & 3) * 4) + l4) ^ (i & 7)) * 8];
            }
            #pragma unroll
            for (int mf = 0; mf < 4; ++mf)
                acc[mf] = __builtin_amdgcn_mfma_f32_16x16x32_bf16(af[mf], wreg[kb], acc[mf], 0, 0, 0);
        }

        // A fully consumed -> barrier, then prefetch next tile's A DMA
        if (!LEAF) {
            asm volatile("s_waitcnt lgkmcnt(0)" ::: "memory");
            __builtin_amdgcn_sched_barrier(0);
            __builtin_amdgcn_s_barrier();
            __builtin_amdgcn_sched_barrier(0);
            if (tnext < ntiles) {
                const unsigned short* src = embIn + (size_t)tnext * 16384;
                #pragma unroll
                for (int it = 0; it < 4; ++it) {
                    int q = t + it * 512;
                    cp16_g2l(src + q * 8, &A_lds[0][0][0] + q * 8);
                }
            }
        }

        #pragma unroll
        for (int kb = 8; kb < 12; ++kb) {  // u
            bf16x8 af[4];
            #pragma unroll
            for (int mf = 0; mf < 4; ++mf) {
                int i = mf * 16 + l15;
                af[mf] = *(const bf16x8*)&u_lds[i][((((kb - 8) * 4) + l4) ^ (i & 7)) * 8];
            }
            #pragma unroll
            for (int mf = 0; mf < 4; ++mf)
                acc[mf] = __builtin_amdgcn_mfma_f32_16x16x32_bf16(af[mf], wreg[kb], acc[mf], 0, 0, 0);
        }

        // ======== epilogue ========
        if (LAST) {
            #pragma unroll
            for (int mf = 0; mf < 4; ++mf)
                #pragma unroll
                for (int r = 0; r < 4; ++r) {
                    int i = mf * 16 + l4 * 4 + r;
                    int n = wid * 16 + l15;
                    outF[(size_t)(tile * 64 + i) * 128 + n] = fmaxf(acc[mf][r], 0.f);
                }
        } else {
            // u_lds reads (kb8-11) done by all waves before reuse as bounce buffer
            asm volatile("s_waitcnt lgkmcnt(0)" ::: "memory");
            __builtin_amdgcn_sched_barrier(0);
            __builtin_amdgcn_s_barrier();        // [A]
            unsigned short* ep = &u_lds[0][0];
            #pragma unroll
            for (int mf = 0; mf < 4; ++mf)
                #pragma unroll
                for (int r = 0; r < 4; ++r) {
                    int i = mf * 16 + l4 * 4 + r;
                    int n = wid * 16 + l15;
                    int row = (i & 1) * 32 + (i >> 1);   // image row within tile
                    ep[row * 128 + (n ^ (((i >> 1) & 7) << 3))] = f2bf(fmaxf(acc[mf][r], 0.f));
                }
            asm volatile("s_waitcnt lgkmcnt(0)" ::: "memory");
            __builtin_amdgcn_s_barrier();        // [B] ep writes visible
            bf16x8 ev0 = *(const bf16x8*)&ep[(0 * 512 + t) * 8];
            bf16x8 ev1 = *(const bf16x8*)&ep[(1 * 512 + t) * 8];
            asm volatile("s_waitcnt lgkmcnt(0)" ::: "memory");
            __builtin_amdgcn_sched_barrier(0);
            __builtin_amdgcn_s_barrier();        // [C] reads done -> u_lds free next iter
            size_t gbase = (size_t)(tile >> 1) * 16384 + (size_t)(tile & 1) * 4096;
            unsigned short* gp = embOut + gbase;
            *(bf16x8*)(gp + (size_t)((0 * 512 + t) >> 9) * 8192 + ((0 * 512 + t) & 511) * 8) = ev0;
            *(bf16x8*)(gp + (size_t)((1 * 512 + t) >> 9) * 8192 + ((1 * 512 + t) & 511) * 8) = ev1;
        }
    }
}

extern "C" void kernel_launch(void* const* d_in, const int* in_sizes, int n_in,
                              void* d_out, int out_size, void* d_ws, size_t ws_size,
                              hipStream_t stream) {
    const float* contents[10];
    for (int j = 0; j < 10; ++j) contents[j] = (const float*)d_in[j];
    const float* Wu = (const float*)d_in[19];
    const float* bu = (const float*)d_in[20];
    const float* Wh = (const float*)d_in[21];
    const float* bh = (const float*)d_in[22];

    unsigned short* Wbf  = (unsigned short*)d_ws;                                     // 96 KiB
    unsigned short* bufE = (unsigned short*)((char*)d_ws + (1u << 20));               // 64 MiB (even-level embs)
    unsigned short* bufO = (unsigned short*)((char*)d_ws + (1u << 20) + (64u << 20)); // 32 MiB (odd-level embs)

    k_cvtW<<<128, 384, 0, stream>>>(Wh, Wbf);

    // level 8 (leaf-fused): children = relu(contents_9 @ Wu^T + bu) computed in-kernel
    {
        int ntiles = (1024 << 8) >> 6;   // 4096
        int grid = ntiles < 512 ? ntiles : 512;
        k_level<1, 0><<<grid, 512, 0, stream>>>(nullptr, contents[8], contents[9], Wbf,
                                                Wu, bu, bh, bufE, nullptr, 1024 << 8);
    }
    // levels 7..1
    for (int j = 7; j >= 1; --j) {
        int n = 1024 << j;
        const unsigned short* in = (j & 1) ? bufE : bufO;  // emb_{j+1}
        unsigned short* outp     = (j & 1) ? bufO : bufE;  // emb_j
        int ntiles = n >> 6;
        int grid = ntiles < 512 ? ntiles : 512;
        k_level<0, 0><<<grid, 512, 0, stream>>>(in, contents[j], nullptr, Wbf,
                                                Wu, bu, bh, outp, nullptr, n);
    }
    // level 0 -> f32 output (16 tiles)
    k_level<0, 1><<<16, 512, 0, stream>>>(bufO, contents[0], nullptr, Wbf,
                                          Wu, bu, bh, nullptr, (float*)d_out, 1024);
}

// Round 12
// 179.877 us; speedup vs baseline: 1.5722x; 1.0987x over previous
//
#include <hip/hip_runtime.h>
#include <hip/hip_bf16.h>

typedef __attribute__((ext_vector_type(8))) short bf16x8;
typedef __attribute__((ext_vector_type(4))) float f32x4;

__device__ __forceinline__ unsigned short f2bf(float f) {
    __hip_bfloat16 h = __float2bfloat16(f);   // RTNE; compiler emits v_cvt_pk_bf16_f32 for pairs
    union { __hip_bfloat16 h; unsigned short u; } v; v.h = h;
    return v.u;
}

__device__ __forceinline__ void cp16_g2l(const void* g, void* l) {
    __builtin_amdgcn_global_load_lds(
        (const __attribute__((address_space(1))) unsigned int*)g,
        (__attribute__((address_space(3))) unsigned int*)l, 16, 0, 0);
}

// ---- one-time: W_h f32 [128][384] -> plain bf16 row-major image in ws ----
__global__ __launch_bounds__(384) void k_cvtW(const float* __restrict__ Wh,
                                              unsigned short* __restrict__ Wbf) {
    int n = blockIdx.x, k = threadIdx.x;
    Wbf[n * 384 + k] = f2bf(Wh[n * 384 + k]);
}

// Block tile: 64 own rows x 128 cols, EIGHT waves (wave = 64 rows x 16-col slice).
// W_h slice in registers (48 VGPR, pinned). Wu/bu fragment table in LDS.
// Own-contents prefetched one tile ahead (8 VGPR). LEAF child contents loaded
// DIRECTLY in the child-u phase (prefetching them cost 24 VGPR -> unified
// 128-reg cap overflow -> scratch spills, +28MB HBM writes — round 11).
// A-tile DMA prefetched one tile ahead, drained by counted vmcnt(4) at the
// phase barrier (4 DMA oldest; 2 stores + 2 contents newer stay in flight).
template<int LEAF, int LAST>
__global__ __launch_bounds__(512, 4) void k_level(
    const unsigned short* __restrict__ embIn,
    const float* __restrict__ contO,   // [n][8] own contents
    const float* __restrict__ contC,   // [2n][8] child contents (LEAF only)
    const unsigned short* __restrict__ Wbf, // bf16 W image [128*384]
    const float* __restrict__ Wu,      // [128][8]
    const float* __restrict__ bu,      // [128]
    const float* __restrict__ bh,      // [128]
    unsigned short* __restrict__ embOut, // child-image layout
    float* __restrict__ outF,          // row-major f32 (LAST)
    int n_nodes)
{
    // LDS: 32K (A) + 16K (u) + 4K (wu) = 52 KiB -> 2 blocks/CU (16 waves)
    __shared__ __align__(16) unsigned short A_lds[2][64][128]; // [cc][il][n^swz]
    __shared__ __align__(16) unsigned short u_lds[64][128];    // [i][n^swz] (+ epilogue bounce)
    __shared__ __align__(16) unsigned short wu_lds[8][32][8];  // [nf][l4*16+l15][e]

    const int t = threadIdx.x, lane = t & 63, wid = t >> 6;    // 8 waves
    const int l15 = lane & 15, l4 = lane >> 4;
    const int wrow = wid & 3;        // u-phase row quarter (rows wrow*16..+16)
    const int wcolh = wid >> 2;      // u-phase col half (cols wcolh*64..+64)

    // ---- persistent W fragments: wave's 16-col slice, 12 K-blocks (48 VGPR) ----
    bf16x8 wreg[12];
    {
        int n = wid * 16 + l15;
        #pragma unroll
        for (int kb = 0; kb < 12; ++kb)
            wreg[kb] = *reinterpret_cast<const bf16x8*>(Wbf + n * 384 + kb * 32 + l4 * 8);
    }
    #pragma unroll
    for (int kb = 0; kb < 12; ++kb)
        asm volatile("" : "+v"(wreg[kb]));

    // ---- Wu/bu fragment table (B-op of K=32-padded u-GEMM), written by wave 0 ----
    if (wid == 0 && l4 < 2) {
        #pragma unroll
        for (int nf = 0; nf < 8; ++nf) {
            int n = nf * 16 + l15;
            bf16x8 v = {0, 0, 0, 0, 0, 0, 0, 0};
            if (l4 == 0) {
                #pragma unroll
                for (int k = 0; k < 8; ++k) ((unsigned short*)&v)[k] = f2bf(Wu[n * 8 + k]);
            } else {
                ((unsigned short*)&v)[0] = f2bf(bu[n]);   // bias column (k=8)
            }
            *(bf16x8*)&wu_lds[nf][l4 * 16 + l15][0] = v;
        }
    }
    const float bhv = bh[wid * 16 + l15];

    bf16x8 zeroA = {0, 0, 0, 0, 0, 0, 0, 0};
    bf16x8 onesA = zeroA; ((unsigned short*)&onesA)[0] = 0x3F80;  // 1.0 at k=8

    const int ntiles = n_nodes >> 6;
    const int stride = gridDim.x;
    const int tile0 = blockIdx.x;
    if (tile0 >= ntiles) return;

    // ---- own-contents prefetch registers (A-fragment lanes: l4==0 holds the row) ----
    f32x4 cO0 = {0,0,0,0}, cO1 = {0,0,0,0};

    // ---- prologue: tile0 A DMA + own contents ----
    if (!LEAF) {
        const unsigned short* src = embIn + (size_t)tile0 * 16384;
        #pragma unroll
        for (int it = 0; it < 4; ++it) {
            int q = t + it * 512;
            cp16_g2l(src + q * 8, &A_lds[0][0][0] + q * 8);
        }
    }
    if (l4 == 0) {
        const float* p = contO + ((size_t)tile0 * 64 + wrow * 16 + l15) * 8;
        cO0 = *(const f32x4*)p; cO1 = *(const f32x4*)(p + 4);
    }
    __syncthreads();  // drains prologue DMA/loads + wu_lds visible

    for (int tile = tile0; tile < ntiles; tile += stride) {
        const int tnext = tile + stride;

        // ======== u-phase: rows wrow*16..+16, cols wcolh*64..+64 (4 MFMA) ========
        {
            bf16x8 au = zeroA;
            if (l4 == 0) {
                #pragma unroll
                for (int e = 0; e < 4; ++e) {
                    ((unsigned short*)&au)[e]     = f2bf(cO0[e]);
                    ((unsigned short*)&au)[e + 4] = f2bf(cO1[e]);
                }
            } else if (l4 == 1) au = onesA;
            #pragma unroll
            for (int nfi = 0; nfi < 4; ++nfi) {
                int nf = wcolh * 4 + nfi;
                bf16x8 wv = zeroA;
                if (l4 < 2) wv = *(const bf16x8*)&wu_lds[nf][l4 * 16 + l15][0];
                f32x4 z = {0.f, 0.f, 0.f, 0.f};
                z = __builtin_amdgcn_mfma_f32_16x16x32_bf16(au, wv, z, 0, 0, 0);
                #pragma unroll
                for (int r = 0; r < 4; ++r) {
                    int iu = wrow * 16 + l4 * 4 + r;
                    int n = nf * 16 + l15;
                    u_lds[iu][n ^ ((iu & 7) << 3)] = f2bf(fmaxf(z[r], 0.f));
                }
            }
        }
        if (LEAF) {  // child-u: child rows wrow*32..+32, cols wcolh*64..+64 (8 MFMA)
            // child contents loaded DIRECTLY (no prefetch state -> no spills)
            const float* pcBase = contC + ((size_t)tile * 128 + wrow * 32 + l15) * 8;
            #pragma unroll
            for (int rb = 0; rb < 2; ++rb) {
                bf16x8 ac = zeroA;
                if (l4 == 0) {
                    f32x4 a  = *(const f32x4*)(pcBase + rb * 128);
                    f32x4 b2 = *(const f32x4*)(pcBase + rb * 128 + 4);
                    #pragma unroll
                    for (int e = 0; e < 4; ++e) {
                        ((unsigned short*)&ac)[e]     = f2bf(a[e]);
                        ((unsigned short*)&ac)[e + 4] = f2bf(b2[e]);
                    }
                } else if (l4 == 1) ac = onesA;
                #pragma unroll
                for (int nfi = 0; nfi < 4; ++nfi) {
                    int nf = wcolh * 4 + nfi;
                    bf16x8 wv = zeroA;
                    if (l4 < 2) wv = *(const bf16x8*)&wu_lds[nf][l4 * 16 + l15][0];
                    f32x4 z = {0.f, 0.f, 0.f, 0.f};
                    z = __builtin_amdgcn_mfma_f32_16x16x32_bf16(ac, wv, z, 0, 0, 0);
                    #pragma unroll
                    for (int r = 0; r < 4; ++r) {
                        int rr = wrow * 32 + rb * 16 + l4 * 4 + r;  // local child row
                        int cc = rr & 1, il = rr >> 1;
                        int n = nf * 16 + l15;
                        A_lds[cc][il][n ^ ((il & 7) << 3)] = f2bf(fmaxf(z[r], 0.f));
                    }
                }
            }
        }

        // ---- prefetch next tile's own contents (issue-early, consumed next iter) ----
        if (tnext < ntiles && l4 == 0) {
            const float* p = contO + ((size_t)tnext * 64 + wrow * 16 + l15) * 8;
            cO0 = *(const f32x4*)p; cO1 = *(const f32x4*)(p + 4);
        }

        // ======== phase barrier: A slabs ready (counted vmcnt), u/A visible ========
        if (!LEAF) asm volatile("s_waitcnt vmcnt(4)" ::: "memory");  // drain 4 oldest (DMA); leave 2 stores + 2 contents
        asm volatile("s_waitcnt lgkmcnt(0)" ::: "memory");
        __builtin_amdgcn_sched_barrier(0);
        __builtin_amdgcn_s_barrier();
        __builtin_amdgcn_sched_barrier(0);

        // ======== main GEMM: K=384 = [child0 | child1 | u], wave cols wid*16..+16 ========
        f32x4 acc[4];
        #pragma unroll
        for (int mf = 0; mf < 4; ++mf) acc[mf] = (f32x4){bhv, bhv, bhv, bhv};

        #pragma unroll
        for (int kb = 0; kb < 8; ++kb) {   // A slabs
            bf16x8 af[4];
            #pragma unroll
            for (int mf = 0; mf < 4; ++mf) {
                int i = mf * 16 + l15;
                af[mf] = *(const bf16x8*)&A_lds[kb >> 2][i][((((kb & 3) * 4) + l4) ^ (i & 7)) * 8];
            }
            #pragma unroll
            for (int mf = 0; mf < 4; ++mf)
                acc[mf] = __builtin_amdgcn_mfma_f32_16x16x32_bf16(af[mf], wreg[kb], acc[mf], 0, 0, 0);
        }

        // A fully consumed -> barrier, then prefetch next tile's A DMA
        if (!LEAF) {
            asm volatile("s_waitcnt lgkmcnt(0)" ::: "memory");
            __builtin_amdgcn_sched_barrier(0);
            __builtin_amdgcn_s_barrier();
            __builtin_amdgcn_sched_barrier(0);
            if (tnext < ntiles) {
                const unsigned short* src = embIn + (size_t)tnext * 16384;
                #pragma unroll
                for (int it = 0; it < 4; ++it) {
                    int q = t + it * 512;
                    cp16_g2l(src + q * 8, &A_lds[0][0][0] + q * 8);
                }
            }
        }

        #pragma unroll
        for (int kb = 8; kb < 12; ++kb) {  // u
            bf16x8 af[4];
            #pragma unroll
            for (int mf = 0; mf < 4; ++mf) {
                int i = mf * 16 + l15;
                af[mf] = *(const bf16x8*)&u_lds[i][((((kb - 8) * 4) + l4) ^ (i & 7)) * 8];
            }
            #pragma unroll
            for (int mf = 0; mf < 4; ++mf)
                acc[mf] = __builtin_amdgcn_mfma_f32_16x16x32_bf16(af[mf], wreg[kb], acc[mf], 0, 0, 0);
        }

        // ======== epilogue ========
        if (LAST) {
            #pragma unroll
            for (int mf = 0; mf < 4; ++mf)
                #pragma unroll
                for (int r = 0; r < 4; ++r) {
                    int i = mf * 16 + l4 * 4 + r;
                    int n = wid * 16 + l15;
                    outF[(size_t)(tile * 64 + i) * 128 + n] = fmaxf(acc[mf][r], 0.f);
                }
        } else {
            // u_lds reads (kb8-11) done by all waves before reuse as bounce buffer
            asm volatile("s_waitcnt lgkmcnt(0)" ::: "memory");
            __builtin_amdgcn_sched_barrier(0);
            __builtin_amdgcn_s_barrier();        // [A]
            unsigned short* ep = &u_lds[0][0];
            #pragma unroll
            for (int mf = 0; mf < 4; ++mf)
                #pragma unroll
                for (int r = 0; r < 4; ++r) {
                    int i = mf * 16 + l4 * 4 + r;
                    int n = wid * 16 + l15;
                    int row = (i & 1) * 32 + (i >> 1);   // image row within tile
                    ep[row * 128 + (n ^ (((i >> 1) & 7) << 3))] = f2bf(fmaxf(acc[mf][r], 0.f));
                }
            asm volatile("s_waitcnt lgkmcnt(0)" ::: "memory");
            __builtin_amdgcn_s_barrier();        // [B] ep writes visible
            bf16x8 ev0 = *(const bf16x8*)&ep[(0 * 512 + t) * 8];
            bf16x8 ev1 = *(const bf16x8*)&ep[(1 * 512 + t) * 8];
            asm volatile("s_waitcnt lgkmcnt(0)" ::: "memory");
            __builtin_amdgcn_sched_barrier(0);
            __builtin_amdgcn_s_barrier();        // [C] reads done -> u_lds free next iter
            size_t gbase = (size_t)(tile >> 1) * 16384 + (size_t)(tile & 1) * 4096;
            unsigned short* gp = embOut + gbase;
            *(bf16x8*)(gp + (size_t)((0 * 512 + t) >> 9) * 8192 + ((0 * 512 + t) & 511) * 8) = ev0;
            *(bf16x8*)(gp + (size_t)((1 * 512 + t) >> 9) * 8192 + ((1 * 512 + t) & 511) * 8) = ev1;
        }
    }
}

extern "C" void kernel_launch(void* const* d_in, const int* in_sizes, int n_in,
                              void* d_out, int out_size, void* d_ws, size_t ws_size,
                              hipStream_t stream) {
    const float* contents[10];
    for (int j = 0; j < 10; ++j) contents[j] = (const float*)d_in[j];
    const float* Wu = (const float*)d_in[19];
    const float* bu = (const float*)d_in[20];
    const float* Wh = (const float*)d_in[21];
    const float* bh = (const float*)d_in[22];

    unsigned short* Wbf  = (unsigned short*)d_ws;                                     // 96 KiB
    unsigned short* bufE = (unsigned short*)((char*)d_ws + (1u << 20));               // 64 MiB (even-level embs)
    unsigned short* bufO = (unsigned short*)((char*)d_ws + (1u << 20) + (64u << 20)); // 32 MiB (odd-level embs)

    k_cvtW<<<128, 384, 0, stream>>>(Wh, Wbf);

    // level 8 (leaf-fused): children = relu(contents_9 @ Wu^T + bu) computed in-kernel
    {
        int ntiles = (1024 << 8) >> 6;   // 4096
        int grid = ntiles < 512 ? ntiles : 512;
        k_level<1, 0><<<grid, 512, 0, stream>>>(nullptr, contents[8], contents[9], Wbf,
                                                Wu, bu, bh, bufE, nullptr, 1024 << 8);
    }
    // levels 7..1
    for (int j = 7; j >= 1; --j) {
        int n = 1024 << j;
        const unsigned short* in = (j & 1) ? bufE : bufO;  // emb_{j+1}
        unsigned short* outp     = (j & 1) ? bufO : bufE;  // emb_j
        int ntiles = n >> 6;
        int grid = ntiles < 512 ? ntiles : 512;
        k_level<0, 0><<<grid, 512, 0, stream>>>(in, contents[j], nullptr, Wbf,
                                                Wu, bu, bh, outp, nullptr, n);
    }
    // level 0 -> f32 output (16 tiles)
    k_level<0, 1><<<16, 512, 0, stream>>>(bufO, contents[0], nullptr, Wbf,
                                          Wu, bu, bh, nullptr, (float*)d_out, 1024);
}

// Round 13
// 174.443 us; speedup vs baseline: 1.6212x; 1.0312x over previous
//
#include <hip/hip_runtime.h>
#include <hip/hip_bf16.h>

typedef __attribute__((ext_vector_type(8))) short bf16x8;
typedef __attribute__((ext_vector_type(4))) float f32x4;
typedef __attribute__((ext_vector_type(4))) unsigned short u16x4;

__device__ __forceinline__ unsigned short f2bf(float f) {
    __hip_bfloat16 h = __float2bfloat16(f);   // RTNE; pairs fuse to v_cvt_pk_bf16_f32
    union { __hip_bfloat16 h; unsigned short u; } v; v.h = h;
    return v.u;
}

__device__ __forceinline__ void cp16_g2l(const void* g, void* l) {
    __builtin_amdgcn_global_load_lds(
        (const __attribute__((address_space(1))) unsigned int*)g,
        (__attribute__((address_space(3))) unsigned int*)l, 16, 0, 0);
}

// ---- one-time: W_h f32 [128][384] -> plain bf16 row-major image in ws ----
__global__ __launch_bounds__(384) void k_cvtW(const float* __restrict__ Wh,
                                              unsigned short* __restrict__ Wbf) {
    int n = blockIdx.x, k = threadIdx.x;
    Wbf[n * 384 + k] = f2bf(Wh[n * 384 + k]);
}

// Block tile: 64 own rows x 128 cols, 8 waves (wave = 64 rows x 16-col slice).
// TRANSPOSED COMPUTE: every MFMA is mfma(W_frag, emb_frag) -> D[n][i], so each
// thread owns 4 consecutive COLUMNS of one row -> all result writes are 8B
// chunks (ds_write_b64 / 8B global stores). Same wreg/wu_lds/A-read mappings
// as the validated direct form (A-frag and B-frag lane layouts coincide).
// Barriers/tile: 3 (leaf 2); epilogue LDS bounce eliminated.
template<int LEAF, int LAST>
__global__ __launch_bounds__(512, 4) void k_level(
    const unsigned short* __restrict__ embIn,
    const float* __restrict__ contO,   // [n][8] own contents
    const float* __restrict__ contC,   // [2n][8] child contents (LEAF only)
    const unsigned short* __restrict__ Wbf, // bf16 W image [128*384]
    const float* __restrict__ Wu,      // [128][8]
    const float* __restrict__ bu,      // [128]
    const float* __restrict__ bh,      // [128]
    unsigned short* __restrict__ embOut, // child-image layout
    float* __restrict__ outF,          // row-major f32 (LAST)
    int n_nodes)
{
    // LDS: 32K (A) + 16K (u) + 4K (wu) = 52 KiB -> 2 blocks/CU (16 waves)
    __shared__ __align__(16) unsigned short A_lds[2][64][128]; // [cc][il][n^swz]
    __shared__ __align__(16) unsigned short u_lds[64][128];    // [i][n^swz]
    __shared__ __align__(16) unsigned short wu_lds[8][32][8];  // [nf][l4*16+l15][e]

    const int t = threadIdx.x, lane = t & 63, wid = t >> 6;    // 8 waves
    const int l15 = lane & 15, l4 = lane >> 4;
    const int wrow = wid & 3;        // u-phase row quarter
    const int wcolh = wid >> 2;      // u-phase col half

    // ---- persistent W fragments: wave's 16-col slice (48 VGPR, pinned) ----
    // lane (l4,l15) holds W[n = wid*16 + l15][k = kb*32 + l4*8 + e]
    bf16x8 wreg[12];
    {
        int n = wid * 16 + l15;
        #pragma unroll
        for (int kb = 0; kb < 12; ++kb)
            wreg[kb] = *reinterpret_cast<const bf16x8*>(Wbf + n * 384 + kb * 32 + l4 * 8);
    }
    #pragma unroll
    for (int kb = 0; kb < 12; ++kb)
        asm volatile("" : "+v"(wreg[kb]));

    // ---- Wu/bu fragment table (now the A-operand of the u-GEMM) ----
    if (wid == 0 && l4 < 2) {
        #pragma unroll
        for (int nf = 0; nf < 8; ++nf) {
            int n = nf * 16 + l15;
            bf16x8 v = {0, 0, 0, 0, 0, 0, 0, 0};
            if (l4 == 0) {
                #pragma unroll
                for (int k = 0; k < 8; ++k) ((unsigned short*)&v)[k] = f2bf(Wu[n * 8 + k]);
            } else {
                ((unsigned short*)&v)[0] = f2bf(bu[n]);   // bias column (k=8)
            }
            *(bf16x8*)&wu_lds[nf][l4 * 16 + l15][0] = v;
        }
    }
    // bias for D[n][i]: n = wid*16 + l4*4 + r -> vector load
    const f32x4 bh4 = *(const f32x4*)&bh[wid * 16 + l4 * 4];

    bf16x8 zeroA = {0, 0, 0, 0, 0, 0, 0, 0};
    bf16x8 onesA = zeroA; ((unsigned short*)&onesA)[0] = 0x3F80;  // 1.0 at k=8

    const int ntiles = n_nodes >> 6;
    const int stride = gridDim.x;
    const int tile0 = blockIdx.x;
    if (tile0 >= ntiles) return;

    f32x4 cO0 = {0,0,0,0}, cO1 = {0,0,0,0};

    // ---- prologue: tile0 A DMA + own contents ----
    if (!LEAF) {
        const unsigned short* src = embIn + (size_t)tile0 * 16384;
        #pragma unroll
        for (int it = 0; it < 4; ++it) {
            int q = t + it * 512;
            cp16_g2l(src + q * 8, &A_lds[0][0][0] + q * 8);
        }
    }
    if (l4 == 0) {
        const float* p = contO + ((size_t)tile0 * 64 + wrow * 16 + l15) * 8;
        cO0 = *(const f32x4*)p; cO1 = *(const f32x4*)(p + 4);
    }
    __syncthreads();  // drains prologue DMA/loads; wu_lds visible

    for (int tile = tile0; tile < ntiles; tile += stride) {
        const int tnext = tile + stride;

        // ======== u-phase: D[n][i], i = wrow*16+l15, n in wcolh half ========
        {
            bf16x8 cb = zeroA;                 // B-operand: cont^T
            if (l4 == 0) {
                #pragma unroll
                for (int e = 0; e < 4; ++e) {
                    ((unsigned short*)&cb)[e]     = f2bf(cO0[e]);
                    ((unsigned short*)&cb)[e + 4] = f2bf(cO1[e]);
                }
            } else if (l4 == 1) cb = onesA;
            const int i = wrow * 16 + l15;
            #pragma unroll
            for (int nfi = 0; nfi < 4; ++nfi) {
                int nf = wcolh * 4 + nfi;
                bf16x8 wv = zeroA;
                if (l4 < 2) wv = *(const bf16x8*)&wu_lds[nf][l4 * 16 + l15][0];
                f32x4 z = {0.f, 0.f, 0.f, 0.f};
                z = __builtin_amdgcn_mfma_f32_16x16x32_bf16(wv, cb, z, 0, 0, 0);
                u16x4 pk;
                #pragma unroll
                for (int r = 0; r < 4; ++r) pk[r] = f2bf(fmaxf(z[r], 0.f));
                int n4 = nf * 16 + l4 * 4;
                *(u16x4*)&u_lds[i][n4 ^ ((i & 7) << 3)] = pk;
            }
        }
        if (LEAF) {  // child-u: D[n][child], child = wrow*32 + rb*16 + l15
            const float* pcBase = contC + ((size_t)tile * 128 + wrow * 32 + l15) * 8;
            #pragma unroll
            for (int rb = 0; rb < 2; ++rb) {
                bf16x8 cb = zeroA;
                if (l4 == 0) {
                    f32x4 a  = *(const f32x4*)(pcBase + rb * 128);
                    f32x4 b2 = *(const f32x4*)(pcBase + rb * 128 + 4);
                    #pragma unroll
                    for (int e = 0; e < 4; ++e) {
                        ((unsigned short*)&cb)[e]     = f2bf(a[e]);
                        ((unsigned short*)&cb)[e + 4] = f2bf(b2[e]);
                    }
                } else if (l4 == 1) cb = onesA;
                const int rr = wrow * 32 + rb * 16 + l15;   // local child row
                const int cc = rr & 1, il = rr >> 1;
                #pragma unroll
                for (int nfi = 0; nfi < 4; ++nfi) {
                    int nf = wcolh * 4 + nfi;
                    bf16x8 wv = zeroA;
                    if (l4 < 2) wv = *(const bf16x8*)&wu_lds[nf][l4 * 16 + l15][0];
                    f32x4 z = {0.f, 0.f, 0.f, 0.f};
                    z = __builtin_amdgcn_mfma_f32_16x16x32_bf16(wv, cb, z, 0, 0, 0);
                    u16x4 pk;
                    #pragma unroll
                    for (int r = 0; r < 4; ++r) pk[r] = f2bf(fmaxf(z[r], 0.f));
                    int n4 = nf * 16 + l4 * 4;
                    *(u16x4*)&A_lds[cc][il][n4 ^ ((il & 7) << 3)] = pk;
                }
            }
        }

        // ---- prefetch next tile's own contents (ALWAYS issued, clamped addr:
        //      keeps the vmcnt queue uniform on the last iteration) ----
        {
            int tn = (tnext < ntiles) ? tnext : tile;
            if (l4 == 0) {
                const float* p = contO + ((size_t)tn * 64 + wrow * 16 + l15) * 8;
                cO0 = *(const f32x4*)p; cO1 = *(const f32x4*)(p + 4);
            }
        }

        // ======== phase barrier: A ready (counted vmcnt), u/A LDS visible ========
        if (!LEAF) asm volatile("s_waitcnt vmcnt(6)" ::: "memory");  // drain 4 DMA; leave 4 stores + 2 loads
        asm volatile("s_waitcnt lgkmcnt(0)" ::: "memory");
        __builtin_amdgcn_sched_barrier(0);
        __builtin_amdgcn_s_barrier();
        __builtin_amdgcn_sched_barrier(0);

        // ======== main GEMM: acc = W·emb^T, D[n = wid*16+l4*4+r][i = mf*16+l15] ========
        f32x4 acc[4];
        #pragma unroll
        for (int mf = 0; mf < 4; ++mf) acc[mf] = bh4;

        #pragma unroll
        for (int kb = 0; kb < 8; ++kb) {   // A slabs (emb as B-operand; reads unchanged)
            bf16x8 af[4];
            #pragma unroll
            for (int mf = 0; mf < 4; ++mf) {
                int i = mf * 16 + l15;
                af[mf] = *(const bf16x8*)&A_lds[kb >> 2][i][((((kb & 3) * 4) + l4) ^ (i & 7)) * 8];
            }
            #pragma unroll
            for (int mf = 0; mf < 4; ++mf)
                acc[mf] = __builtin_amdgcn_mfma_f32_16x16x32_bf16(wreg[kb], af[mf], acc[mf], 0, 0, 0);
        }

        // A consumed -> barrier, then prefetch next tile's A DMA
        if (!LEAF) {
            asm volatile("s_waitcnt lgkmcnt(0)" ::: "memory");
            __builtin_amdgcn_sched_barrier(0);
            __builtin_amdgcn_s_barrier();
            __builtin_amdgcn_sched_barrier(0);
            if (tnext < ntiles) {
                const unsigned short* src = embIn + (size_t)tnext * 16384;
                #pragma unroll
                for (int it = 0; it < 4; ++it) {
                    int q = t + it * 512;
                    cp16_g2l(src + q * 8, &A_lds[0][0][0] + q * 8);
                }
            }
        }

        #pragma unroll
        for (int kb = 8; kb < 12; ++kb) {  // u
            bf16x8 af[4];
            #pragma unroll
            for (int mf = 0; mf < 4; ++mf) {
                int i = mf * 16 + l15;
                af[mf] = *(const bf16x8*)&u_lds[i][((((kb - 8) * 4) + l4) ^ (i & 7)) * 8];
            }
            #pragma unroll
            for (int mf = 0; mf < 4; ++mf)
                acc[mf] = __builtin_amdgcn_mfma_f32_16x16x32_bf16(wreg[kb], af[mf], acc[mf], 0, 0, 0);
        }

        // ======== epilogue: direct 8B/16B stores (thread owns 4 consecutive cols) ========
        if (LAST) {
            #pragma unroll
            for (int mf = 0; mf < 4; ++mf) {
                int i = mf * 16 + l15;
                f32x4 o;
                #pragma unroll
                for (int r = 0; r < 4; ++r) o[r] = fmaxf(acc[mf][r], 0.f);
                *(f32x4*)&outF[(size_t)(tile * 64 + i) * 128 + wid * 16 + l4 * 4] = o;
            }
        } else {
            #pragma unroll
            for (int mf = 0; mf < 4; ++mf) {
                int i = mf * 16 + l15;
                int Rg = tile * 64 + i;
                int rr = Rg & 127, cc = rr & 1, il = rr >> 1;
                u16x4 pk;
                #pragma unroll
                for (int r = 0; r < 4; ++r) pk[r] = f2bf(fmaxf(acc[mf][r], 0.f));
                int n4 = wid * 16 + l4 * 4;
                *(u16x4*)&embOut[(size_t)(Rg >> 7) * 16384 + cc * 8192 + il * 128
                                 + (n4 ^ ((il & 7) << 3))] = pk;
            }
        }

        // ======== post barrier: all LDS reads done before next tile's writes ========
        asm volatile("s_waitcnt lgkmcnt(0)" ::: "memory");
        __builtin_amdgcn_sched_barrier(0);
        __builtin_amdgcn_s_barrier();
    }
}

extern "C" void kernel_launch(void* const* d_in, const int* in_sizes, int n_in,
                              void* d_out, int out_size, void* d_ws, size_t ws_size,
                              hipStream_t stream) {
    const float* contents[10];
    for (int j = 0; j < 10; ++j) contents[j] = (const float*)d_in[j];
    const float* Wu = (const float*)d_in[19];
    const float* bu = (const float*)d_in[20];
    const float* Wh = (const float*)d_in[21];
    const float* bh = (const float*)d_in[22];

    unsigned short* Wbf  = (unsigned short*)d_ws;                                     // 96 KiB
    unsigned short* bufE = (unsigned short*)((char*)d_ws + (1u << 20));               // 64 MiB (even-level embs)
    unsigned short* bufO = (unsigned short*)((char*)d_ws + (1u << 20) + (64u << 20)); // 32 MiB (odd-level embs)

    k_cvtW<<<128, 384, 0, stream>>>(Wh, Wbf);

    // level 8 (leaf-fused): children = relu(contents_9 @ Wu^T + bu) computed in-kernel
    {
        int ntiles = (1024 << 8) >> 6;   // 4096
        int grid = ntiles < 512 ? ntiles : 512;
        k_level<1, 0><<<grid, 512, 0, stream>>>(nullptr, contents[8], contents[9], Wbf,
                                                Wu, bu, bh, bufE, nullptr, 1024 << 8);
    }
    // levels 7..1
    for (int j = 7; j >= 1; --j) {
        int n = 1024 << j;
        const unsigned short* in = (j & 1) ? bufE : bufO;  // emb_{j+1}
        unsigned short* outp     = (j & 1) ? bufO : bufE;  // emb_j
        int ntiles = n >> 6;
        int grid = ntiles < 512 ? ntiles : 512;
        k_level<0, 0><<<grid, 512, 0, stream>>>(in, contents[j], nullptr, Wbf,
                                                Wu, bu, bh, outp, nullptr, n);
    }
    // level 0 -> f32 output (16 tiles)
    k_level<0, 1><<<16, 512, 0, stream>>>(bufO, contents[0], nullptr, Wbf,
                                          Wu, bu, bh, nullptr, (float*)d_out, 1024);
}